// Round 16
// baseline (2232.670 us; speedup 1.0000x reference)
//
#include <hip/hip_runtime.h>
#include <cstdint>
#include <cstddef>

typedef __attribute__((ext_vector_type(8))) short short8;
typedef __attribute__((ext_vector_type(4))) float f32x4;
typedef __attribute__((ext_vector_type(4))) unsigned int u32x4;
typedef __attribute__((ext_vector_type(4))) int i32x4;

#define NEG_LOG2E -1.44269504088896340736f
#define MFMA_BF16 __builtin_amdgcn_mfma_f32_16x16x32_bf16
#define MFMA_I8 __builtin_amdgcn_mfma_i32_16x16x64_i8

// ---- helpers -------------------------------------------------------------
static __device__ __forceinline__ unsigned int cvt_pk_bf16(float lo, float hi) {
  unsigned int r;
  asm("v_cvt_pk_bf16_f32 %0, %1, %2" : "=v"(r) : "v"(lo), "v"(hi));
  return r;
}
// xs is pre-scaled by -log2(e): returns sigmoid(x_true)
static __device__ __forceinline__ float sigmoid_scaled(float xs) {
  return __builtin_amdgcn_rcpf(1.0f + __builtin_amdgcn_exp2f(xs));
}

// ===========================================================================
// Kernel 0: per-output-column scales (parallel).  Block = one column j of
// w' = w*NEG_LOG2E: 64 lanes stride K, shuffle-max, lane 0 writes.
// scbuf[j] = s_j/(127*127) (EPI dequant multiplier, folds h's 1/127),
// w127[j] = 127/s_j (quantizer multiplier).
// ===========================================================================
__global__ void wscale_setup(const float* __restrict__ w_rec,
                             float* __restrict__ scbuf,
                             float* __restrict__ w127) {
  const int j = blockIdx.x;      // 0..1023
  const int l = threadIdx.x;     // 0..63
  const float* row = w_rec + (size_t)j * 256;
  float m = 0.f;
#pragma unroll
  for (int k = 0; k < 4; ++k) m = fmaxf(m, fabsf(row[l + 64 * k]));
#pragma unroll
  for (int d = 32; d > 0; d >>= 1) m = fmaxf(m, __shfl_xor(m, d));
  if (l == 0) {
    float s = fmaxf(m * 1.44269504088896f, 1e-30f);
    scbuf[j] = s / 16129.0f;
    w127[j] = 127.0f / s;
  }
}

// ===========================================================================
// Kernel 1: quantize w_rec -> i8 fragment buffer for mfma_i32_16x16x64_i8.
// 256 slots of 1 KB; slot f = w4*64 + q, q = chain*4 + kt (chain = jidx*4+g,
// kt = K-tile of 64).  jts(w4) = {2w4, 2w4+1, 2w4+8, 2w4+9}; ct = jt + 16g.
// Lane l, dwords d0..3, bytes e: q_w[col = ct*16 + (l&15)]
//                                   [k = kt*64 + (l>>4)*16 + 4d + e]
// (r12-verified layout.  Coltile jt's 16 slots start at
//  f_base(jt) = (jt<8) ? (jt>>1)*64+(jt&1)*16 : ((jt-8)>>1)*64+(2+(jt&1))*16.)
// ===========================================================================
__global__ void wfrag_setup_i8(const float* __restrict__ w_rec,
                               const float* __restrict__ w127,
                               unsigned int* __restrict__ wfq) {
  const int f = blockIdx.x;   // 0..255
  const int l = threadIdx.x;  // 0..63
  const int w = f >> 6, q = f & 63;
  const int chain = q >> 2, kt = q & 3;
  const int jidx = chain >> 2, g = chain & 3;
  const int jt = (jidx < 2) ? (2 * w + jidx) : (2 * w + 8 + (jidx - 2));
  const int ct = jt + 16 * g;
  const int j = ct * 16 + (l & 15);
  const float r = w127[j];
  const float* src = w_rec + (size_t)j * 256 + kt * 64 + (l >> 4) * 16;
  u32x4 ov;
#pragma unroll
  for (int d = 0; d < 4; ++d) {
    unsigned int word = 0;
#pragma unroll
    for (int e = 0; e < 4; ++e) {
      int qi = (int)rintf(src[4 * d + e] * NEG_LOG2E * r);
      qi = qi > 127 ? 127 : (qi < -127 ? -127 : qi);
      word |= ((unsigned int)(qi & 255)) << (8 * e);
    }
    ov[d] = word;
  }
  *(u32x4*)(wfq + (size_t)f * 256 + (size_t)l * 4) = ov;
}

// ===========================================================================
// Kernel 2: gx = (x @ w_in^T + b) * -log2(e), bf16-packed.  NEW layout (r16):
// the 4 gate dwords of a (pb, lane) pair are CONTIGUOUS so the scan fetches
// them with one global_load_dwordx4:
//   gx[ ((((t*16+bg)*8 + pb)*64 + lane)*4 + g ] = bf16(ct=2p)|bf16(ct=2p+1)<<16
// where p = pb + 8g (pb = p&7, g = p>>3), lane = bl*16 + (col&15).
// ===========================================================================
static __device__ __forceinline__ short8 ldcvt8(const float* p) {
  f32x4 v0 = *(const f32x4*)p;
  f32x4 v1 = *(const f32x4*)(p + 4);
  u32x4 u;
  u[0] = cvt_pk_bf16(v0[0], v0[1]);
  u[1] = cvt_pk_bf16(v0[2], v0[3]);
  u[2] = cvt_pk_bf16(v1[0], v1[1]);
  u[3] = cvt_pk_bf16(v1[2], v1[3]);
  return __builtin_bit_cast(short8, u);
}

__global__ __launch_bounds__(256) void gemm_gx(const float* __restrict__ x,
                                               const float* __restrict__ w_in,
                                               const float* __restrict__ bias,
                                               unsigned int* __restrict__ gx) {
  const int l = threadIdx.x & 63, wid = threadIdx.x >> 6;
  const int mq = wid >> 1, nq = wid & 1;
  const int mbase = blockIdx.x * 128 + mq * 64;
  const int nbase = blockIdx.y * 128 + nq * 64;
  const int lr = l & 15;
  const int lk = (l >> 4) * 8;

  f32x4 acc[4][4] = {};
#pragma unroll
  for (int kt = 0; kt < 8; ++kt) {
    const int k0 = kt * 32 + lk;
    short8 af[4], bf[4];
#pragma unroll
    for (int mt = 0; mt < 4; ++mt)
      af[mt] = ldcvt8(x + (size_t)(mbase + mt * 16 + lr) * 256 + k0);
#pragma unroll
    for (int nt = 0; nt < 4; ++nt)
      bf[nt] = ldcvt8(w_in + (size_t)(nbase + nt * 16 + lr) * 256 + k0);
#pragma unroll
    for (int mt = 0; mt < 4; ++mt)
#pragma unroll
      for (int nt = 0; nt < 4; ++nt)
        acc[mt][nt] = MFMA_BF16(af[mt], bf[nt], acc[mt][nt], 0, 0, 0);
  }

  float bv[4];
#pragma unroll
  for (int nt = 0; nt < 4; ++nt) bv[nt] = bias[nbase + nt * 16 + lr];

#pragma unroll
  for (int mt = 0; mt < 4; ++mt) {
    const int m0 = mbase + mt * 16;
    const int tt = m0 >> 6;
    const int bg = ((m0 & 63) >> 2) + (l >> 4);
#pragma unroll
    for (int ntp = 0; ntp < 2; ++ntp) {
      const int p = (nbase >> 5) + ntp;   // 0..31
      const int pb = p & 7, g = p >> 3;
#pragma unroll
      for (int r = 0; r < 4; ++r) {
        float e0 = (acc[mt][ntp * 2 + 0][r] + bv[ntp * 2 + 0]) * NEG_LOG2E;
        float e1 = (acc[mt][ntp * 2 + 1][r] + bv[ntp * 2 + 1]) * NEG_LOG2E;
        gx[(((((size_t)tt * 16 + bg) * 8 + pb) * 64) + (r * 16 + lr)) * 4 + g] =
            cvt_pk_bf16(e0, e1);
      }
    }
  }
}

// ===========================================================================
// Kernel 3: scan, 16 waves/block = 4 waves/SIMD (r15 structure).  r16 deltas:
//   * HB8_ROW 272 -> 288: the afv ds_read_b128 bank pattern goes from 4-way
//     (banks 12-15 hit by all four batch-quads at stride 68 dwords) to
//     uniform 2-way at stride 72 -- 2-way is free (m136).
//   * gx prefetch = ONE global_load_dwordx4 (new gx layout groups the 4 gate
//     dwords contiguously per lane) instead of 4 scattered dword loads.
// Wave w owns coltile jt = w: 16 i8 weight frags = 64 AGPRs, 16 MFMAs +
// 1 EPI per step.  h i8 ping-pong in LDS; one raw s_barrier/step.
// ===========================================================================
#define HB8_ROW 288                      // 256B h-row + 32B pad (2-way banks)
#define HB8_SZ (4 * HB8_ROW)             // 1152
#define LDS_TOTAL (2 * HB8_SZ)           // 2304

#define LD4A(i)                                                         \
  asm volatile("global_load_dwordx4 %0, %4, off\n\t"                    \
               "global_load_dwordx4 %1, %4, off offset:1024\n\t"        \
               "global_load_dwordx4 %2, %4, off offset:2048\n\t"        \
               "global_load_dwordx4 %3, %4, off offset:3072"            \
               : "=&a"(wa[4 * (i)]), "=&a"(wa[4 * (i) + 1]),            \
                 "=&a"(wa[4 * (i) + 2]), "=&a"(wa[4 * (i) + 3])         \
               : "v"(pA + 4096 * (i)))

__global__ __launch_bounds__(1024) void rnn_scan(
    const unsigned int* __restrict__ wfq, const float* __restrict__ scbuf,
    const unsigned int* __restrict__ gx, float* __restrict__ out,
    float* __restrict__ hstate, float* __restrict__ cstate, int first) {
  extern __shared__ char lds[];
  char* hb0 = lds;
  char* hb1 = lds + HB8_SZ;

  const int l = threadIdx.x & 63;
  const int w = threadIdx.x >> 6;   // 0..15 -> coltile jt = w
  const int bg = blockIdx.x;        // 0..15 -> batches 4bg..4bg+3
  const int bloc = l >> 4;          // local batch 0..3
  const int col = l & 15;
  const int jt = w;
  const int fbase = (jt < 8) ? ((jt >> 1) * 64 + (jt & 1) * 16)
                             : (((jt - 8) >> 1) * 64 + (2 + (jt & 1)) * 16);

  // ---- 16 weight frags -> AGPR (64 regs); contiguous 16KB region ---------
  i32x4 wa[16];
  {
    const char* pA = (const char*)wfq + (size_t)fbase * 1024 + (size_t)l * 16;
    LD4A(0); LD4A(1); LD4A(2); LD4A(3);
    asm volatile("s_waitcnt vmcnt(0)" ::: "memory");
  }
  // ---- per-column dequant scales (4 per thread) --------------------------
  float scv[4];
#pragma unroll
  for (int g = 0; g < 4; ++g)
    scv[g] = scbuf[(jt + 16 * g) * 16 + col];

  // ---- h / c init ---------------------------------------------------------
  float carr;
  if (first) {
    for (int i = threadIdx.x; i < (2 * HB8_SZ) / 4; i += 1024)
      ((unsigned int*)hb0)[i] = 0u;
    carr = 0.0f;
  } else {
    const size_t idx = (size_t)(bg * 4 + bloc) * 256 + jt * 16 + col;
    carr = cstate[idx];
    const int qi = (int)rintf(hstate[idx] * 127.f);
    *(char*)(hb0 + bloc * HB8_ROW + jt * 16 + col) = (char)qi;
  }

  // ---- prefetch gx(t=0): one dwordx4 (4 gates) ---------------------------
  u32x4 gxA, gxB;
  {
    const unsigned int* g0 =
        gx + ((((size_t)0 * 16 + bg) * 8 + (jt >> 1)) << 8) + 4 * l;
    gxA = *(const u32x4*)g0;
  }
  __syncthreads();

  float* outp = out + (size_t)(bg * 4 + bloc) * 256 + col + jt * 16;
  const int aoff = ((l & 15) >> 2) * HB8_ROW + (l >> 4) * 16;  // A-frag read
  const int hwoff = bloc * HB8_ROW;
  const bool hi = (jt & 1) != 0;

  auto STEP = [&](int t, char* hbR, char* hbW, u32x4& gxC, u32x4& gxN) {
    // next-step gx prefetch: ONE dwordx4 (stays in flight across barrier)
    const int tn = (t + 1 < 512) ? (t + 1) : 511;
    const unsigned int* gn =
        gx + ((((size_t)tn * 16 + bg) * 8 + (jt >> 1)) << 8) + 4 * l;
    gxN = *(const u32x4*)gn;

    // A-frags (i8 h): 4 x ds_read_b128 covers K=256
    const char* hrd = hbR + aoff;
    i32x4 afv[4];
#pragma unroll
    for (int kt = 0; kt < 4; ++kt)
      afv[kt] = *(const i32x4*)(hrd + kt * 64);

    // ---- 4 gate chains x 4 kt, intrinsic MFMAs ----
    i32x4 d0 = {0, 0, 0, 0}, d1 = d0, d2 = d0, d3 = d0;
#pragma unroll
    for (int kt = 0; kt < 4; ++kt) {
      d0 = MFMA_I8(afv[kt], wa[kt], d0, 0, 0, 0);
      d1 = MFMA_I8(afv[kt], wa[4 + kt], d1, 0, 0, 0);
      d2 = MFMA_I8(afv[kt], wa[8 + kt], d2, 0, 0, 0);
      d3 = MFMA_I8(afv[kt], wa[12 + kt], d3, 0, 0, 0);
    }

    // epilogue: dequant -> gates -> c,h update -> global out + LDS i8 h
    {
      const float g0f = hi ? __uint_as_float(gxC[0] & 0xffff0000u)
                           : __uint_as_float(gxC[0] << 16);
      const float g1f = hi ? __uint_as_float(gxC[1] & 0xffff0000u)
                           : __uint_as_float(gxC[1] << 16);
      const float g2f = hi ? __uint_as_float(gxC[2] & 0xffff0000u)
                           : __uint_as_float(gxC[2] << 16);
      const float g3f = hi ? __uint_as_float(gxC[3] & 0xffff0000u)
                           : __uint_as_float(gxC[3] << 16);
      const float gi = sigmoid_scaled(fmaf((float)d0[0], scv[0], g0f));
      const float go = sigmoid_scaled(fmaf((float)d1[0], scv[1], g1f));
      const float gz = sigmoid_scaled(fmaf((float)d2[0], scv[2], g2f));
      const float gf = sigmoid_scaled(fmaf((float)d3[0], scv[3], g3f));
      carr = gf * carr + (gz - gi);
      const float hs = sigmoid_scaled(carr * NEG_LOG2E);
      const float hn = hs - go;
      outp[(size_t)t * 16384] = hn;
      const int qh = (int)rintf(hn * 127.f);
      *(char*)(hbW + hwoff + jt * 16 + col) = (char)qh;
    }

    // raw barrier: LDS-only drain (no "memory" clobber -> no vmcnt(0));
    // gx prefetch loads and out stores stay in flight across the barrier.
    __builtin_amdgcn_sched_barrier(0);
    asm volatile("s_waitcnt lgkmcnt(0)");
    __builtin_amdgcn_s_barrier();
    __builtin_amdgcn_sched_barrier(0);
  };

  for (int tt = 0; tt < 256; ++tt) {
    STEP(2 * tt, hb0, hb1, gxA, gxB);
    STEP(2 * tt + 1, hb1, hb0, gxB, gxA);
  }

  // ---- save state (h via i8 roundtrip == in-chunk path) -------------------
  {
    const size_t idx = (size_t)(bg * 4 + bloc) * 256 + jt * 16 + col;
    const signed char qv =
        *(const signed char*)(hb0 + hwoff + jt * 16 + col);
    hstate[idx] = (float)qv / 127.f;
    cstate[idx] = carr;
  }
}

// ===========================================================================
// Host launcher.  ws layout:
//   [0,256K)        wfq i8 frags
//   [256K,260K)     scbuf (1024 f32)
//   [260K,264K)     w127 (1024 f32)
//   [512K,576K)     hstate fp32 [64][256]
//   [576K,640K)     cstate fp32 [64][256]
//   [1M, 1M+64M)    gx chunk (512 steps, bf16-packed dwordx4 groups)
// ===========================================================================
extern "C" void kernel_launch(void* const* d_in, const int* in_sizes, int n_in,
                              void* d_out, int out_size, void* d_ws,
                              size_t ws_size, hipStream_t stream) {
  const float* x = (const float*)d_in[0];     // [2048][64][256]
  const float* w_in = (const float*)d_in[1];  // [1024][256]
  const float* bias = (const float*)d_in[2];  // [1024]
  const float* wrec = (const float*)d_in[3];  // [1024][256]
  float* out = (float*)d_out;                 // [2048][64][256]
  char* ws = (char*)d_ws;

  unsigned int* wfq = (unsigned int*)ws;
  float* scbuf = (float*)(ws + (256 << 10));
  float* w127 = (float*)(ws + (260 << 10));
  float* hstate = (float*)(ws + (512 << 10));
  float* cstate = (float*)(ws + (576 << 10));
  unsigned int* gxb = (unsigned int*)(ws + (1 << 20));

  (void)in_sizes; (void)n_in; (void)out_size; (void)ws_size;

  wscale_setup<<<dim3(1024), dim3(64), 0, stream>>>(wrec, scbuf, w127);
  wfrag_setup_i8<<<dim3(256), dim3(64), 0, stream>>>(wrec, w127, wfq);

  for (int c = 0; c < 4; ++c) {
    const size_t xoff = (size_t)c * 512 * 64 * 256;
    gemm_gx<<<dim3(256, 8), dim3(256), 0, stream>>>(x + xoff, w_in, bias, gxb);
    rnn_scan<<<dim3(16), dim3(1024), LDS_TOTAL, stream>>>(
        wfq, scbuf, gxb, out + xoff, hstate, cstate, (c == 0) ? 1 : 0);
  }
}

// Round 17
// 2121.596 us; speedup vs baseline: 1.0524x; 1.0524x over previous
//
#include <hip/hip_runtime.h>
#include <cstdint>
#include <cstddef>

typedef __attribute__((ext_vector_type(8))) short short8;
typedef __attribute__((ext_vector_type(4))) float f32x4;
typedef __attribute__((ext_vector_type(4))) unsigned int u32x4;
typedef __attribute__((ext_vector_type(4))) int i32x4;

#define NEG_LOG2E -1.44269504088896340736f
#define MFMA_BF16 __builtin_amdgcn_mfma_f32_16x16x32_bf16
#define MFMA_I8 __builtin_amdgcn_mfma_i32_16x16x64_i8

// ---- helpers -------------------------------------------------------------
static __device__ __forceinline__ unsigned int cvt_pk_bf16(float lo, float hi) {
  unsigned int r;
  asm("v_cvt_pk_bf16_f32 %0, %1, %2" : "=v"(r) : "v"(lo), "v"(hi));
  return r;
}
// xs is pre-scaled by -log2(e): returns sigmoid(x_true)
static __device__ __forceinline__ float sigmoid_scaled(float xs) {
  return __builtin_amdgcn_rcpf(1.0f + __builtin_amdgcn_exp2f(xs));
}

// ===========================================================================
// Kernel 0: per-output-column scales (parallel).  Block = one column j of
// w' = w*NEG_LOG2E: 64 lanes stride K, shuffle-max, lane 0 writes.
// scbuf[j] = s_j/(127*127) (EPI dequant multiplier, folds h's 1/127),
// w127[j] = 127/s_j (quantizer multiplier).
// ===========================================================================
__global__ void wscale_setup(const float* __restrict__ w_rec,
                             float* __restrict__ scbuf,
                             float* __restrict__ w127) {
  const int j = blockIdx.x;      // 0..1023
  const int l = threadIdx.x;     // 0..63
  const float* row = w_rec + (size_t)j * 256;
  float m = 0.f;
#pragma unroll
  for (int k = 0; k < 4; ++k) m = fmaxf(m, fabsf(row[l + 64 * k]));
#pragma unroll
  for (int d = 32; d > 0; d >>= 1) m = fmaxf(m, __shfl_xor(m, d));
  if (l == 0) {
    float s = fmaxf(m * 1.44269504088896f, 1e-30f);
    scbuf[j] = s / 16129.0f;
    w127[j] = 127.0f / s;
  }
}

// ===========================================================================
// Kernel 1: quantize w_rec -> i8 fragment buffer for mfma_i32_16x16x64_i8.
// 256 slots of 1 KB; slot f = w4*64 + q, q = chain*4 + kt (chain = jidx*4+g,
// kt = K-tile of 64).  jts(w4) = {2w4, 2w4+1, 2w4+8, 2w4+9}; ct = jt + 16g.
// Lane l, dwords d0..3, bytes e: q_w[col = ct*16 + (l&15)]
//                                   [k = kt*64 + (l>>4)*16 + 4d + e]
// (r12-verified layout.  Coltile jt's 16 slots start at
//  f_base(jt) = (jt<8) ? (jt>>1)*64+(jt&1)*16 : ((jt-8)>>1)*64+(2+(jt&1))*16.)
// ===========================================================================
__global__ void wfrag_setup_i8(const float* __restrict__ w_rec,
                               const float* __restrict__ w127,
                               unsigned int* __restrict__ wfq) {
  const int f = blockIdx.x;   // 0..255
  const int l = threadIdx.x;  // 0..63
  const int w = f >> 6, q = f & 63;
  const int chain = q >> 2, kt = q & 3;
  const int jidx = chain >> 2, g = chain & 3;
  const int jt = (jidx < 2) ? (2 * w + jidx) : (2 * w + 8 + (jidx - 2));
  const int ct = jt + 16 * g;
  const int j = ct * 16 + (l & 15);
  const float r = w127[j];
  const float* src = w_rec + (size_t)j * 256 + kt * 64 + (l >> 4) * 16;
  u32x4 ov;
#pragma unroll
  for (int d = 0; d < 4; ++d) {
    unsigned int word = 0;
#pragma unroll
    for (int e = 0; e < 4; ++e) {
      int qi = (int)rintf(src[4 * d + e] * NEG_LOG2E * r);
      qi = qi > 127 ? 127 : (qi < -127 ? -127 : qi);
      word |= ((unsigned int)(qi & 255)) << (8 * e);
    }
    ov[d] = word;
  }
  *(u32x4*)(wfq + (size_t)f * 256 + (size_t)l * 4) = ov;
}

// ===========================================================================
// Kernel 2: gx = (x @ w_in^T + b) * -log2(e), bf16-packed in the scan layout
// (4 gate dwords contiguous per (pb,lane) -- r16-verified):
//   gx[ ((((t*16+bg)*8 + pb)*64 + lane)*4 + g ] = bf16(ct=2p)|bf16(ct=2p+1)<<16
// where p = pb + 8g, lane = bl*16 + (col&15).
// NEW (r17): XCD-aware 1-D block decode.  Default dispatch assigns block n
// to XCD n&7; decode bx=(n>>3)&7 (column block), by=(n>>6)*8+(n&7) (row
// tile), so one row-tile's 8 column-blocks run consecutively on ONE XCD and
// its 128KB A-tile stays in that XCD's private L2 (was: 8x re-fetch of the
// whole 128MB x chunk from HBM -> ~150us/chunk gemm, HBM-bound).
// ===========================================================================
static __device__ __forceinline__ short8 ldcvt8(const float* p) {
  f32x4 v0 = *(const f32x4*)p;
  f32x4 v1 = *(const f32x4*)(p + 4);
  u32x4 u;
  u[0] = cvt_pk_bf16(v0[0], v0[1]);
  u[1] = cvt_pk_bf16(v0[2], v0[3]);
  u[2] = cvt_pk_bf16(v1[0], v1[1]);
  u[3] = cvt_pk_bf16(v1[2], v1[3]);
  return __builtin_bit_cast(short8, u);
}

__global__ __launch_bounds__(256) void gemm_gx(const float* __restrict__ x,
                                               const float* __restrict__ w_in,
                                               const float* __restrict__ bias,
                                               unsigned int* __restrict__ gx) {
  const int n = blockIdx.x;            // 0..2047
  const int bx = (n >> 3) & 7;         // column block (8)
  const int by = (n >> 6) * 8 + (n & 7);  // row tile (256), xcd = n&7
  const int l = threadIdx.x & 63, wid = threadIdx.x >> 6;
  const int mq = wid >> 1, nq = wid & 1;
  const int mbase = by * 128 + mq * 64;
  const int nbase = bx * 128 + nq * 64;
  const int lr = l & 15;
  const int lk = (l >> 4) * 8;

  f32x4 acc[4][4] = {};
#pragma unroll
  for (int kt = 0; kt < 8; ++kt) {
    const int k0 = kt * 32 + lk;
    short8 af[4], bf[4];
#pragma unroll
    for (int mt = 0; mt < 4; ++mt)
      af[mt] = ldcvt8(x + (size_t)(mbase + mt * 16 + lr) * 256 + k0);
#pragma unroll
    for (int nt = 0; nt < 4; ++nt)
      bf[nt] = ldcvt8(w_in + (size_t)(nbase + nt * 16 + lr) * 256 + k0);
#pragma unroll
    for (int mt = 0; mt < 4; ++mt)
#pragma unroll
      for (int nt = 0; nt < 4; ++nt)
        acc[mt][nt] = MFMA_BF16(af[mt], bf[nt], acc[mt][nt], 0, 0, 0);
  }

  float bv[4];
#pragma unroll
  for (int nt = 0; nt < 4; ++nt) bv[nt] = bias[nbase + nt * 16 + lr];

#pragma unroll
  for (int mt = 0; mt < 4; ++mt) {
    const int m0 = mbase + mt * 16;
    const int tt = m0 >> 6;
    const int bg = ((m0 & 63) >> 2) + (l >> 4);
#pragma unroll
    for (int ntp = 0; ntp < 2; ++ntp) {
      const int p = (nbase >> 5) + ntp;   // 0..31
      const int pb = p & 7, g = p >> 3;
#pragma unroll
      for (int r = 0; r < 4; ++r) {
        float e0 = (acc[mt][ntp * 2 + 0][r] + bv[ntp * 2 + 0]) * NEG_LOG2E;
        float e1 = (acc[mt][ntp * 2 + 1][r] + bv[ntp * 2 + 1]) * NEG_LOG2E;
        gx[(((((size_t)tt * 16 + bg) * 8 + pb) * 64) + (r * 16 + lr)) * 4 + g] =
            cvt_pk_bf16(e0, e1);
      }
    }
  }
}

// ===========================================================================
// Kernel 3: scan, 16 waves/block = 4 waves/SIMD (r16-verified, UNCHANGED).
// Wave w owns coltile jt = w: 16 i8 weight frags = 64 AGPRs, 16 MFMAs +
// 1 EPI per step.  HB8_ROW=288 (2-way LDS banks, free); gx prefetch = one
// dwordx4; h i8 ping-pong in LDS; one raw s_barrier/step (LDS-only drain).
// ===========================================================================
#define HB8_ROW 288                      // 256B h-row + 32B pad (2-way banks)
#define HB8_SZ (4 * HB8_ROW)             // 1152
#define LDS_TOTAL (2 * HB8_SZ)           // 2304

#define LD4A(i)                                                         \
  asm volatile("global_load_dwordx4 %0, %4, off\n\t"                    \
               "global_load_dwordx4 %1, %4, off offset:1024\n\t"        \
               "global_load_dwordx4 %2, %4, off offset:2048\n\t"        \
               "global_load_dwordx4 %3, %4, off offset:3072"            \
               : "=&a"(wa[4 * (i)]), "=&a"(wa[4 * (i) + 1]),            \
                 "=&a"(wa[4 * (i) + 2]), "=&a"(wa[4 * (i) + 3])         \
               : "v"(pA + 4096 * (i)))

__global__ __launch_bounds__(1024) void rnn_scan(
    const unsigned int* __restrict__ wfq, const float* __restrict__ scbuf,
    const unsigned int* __restrict__ gx, float* __restrict__ out,
    float* __restrict__ hstate, float* __restrict__ cstate, int first) {
  extern __shared__ char lds[];
  char* hb0 = lds;
  char* hb1 = lds + HB8_SZ;

  const int l = threadIdx.x & 63;
  const int w = threadIdx.x >> 6;   // 0..15 -> coltile jt = w
  const int bg = blockIdx.x;        // 0..15 -> batches 4bg..4bg+3
  const int bloc = l >> 4;          // local batch 0..3
  const int col = l & 15;
  const int jt = w;
  const int fbase = (jt < 8) ? ((jt >> 1) * 64 + (jt & 1) * 16)
                             : (((jt - 8) >> 1) * 64 + (2 + (jt & 1)) * 16);

  // ---- 16 weight frags -> AGPR (64 regs); contiguous 16KB region ---------
  i32x4 wa[16];
  {
    const char* pA = (const char*)wfq + (size_t)fbase * 1024 + (size_t)l * 16;
    LD4A(0); LD4A(1); LD4A(2); LD4A(3);
    asm volatile("s_waitcnt vmcnt(0)" ::: "memory");
  }
  // ---- per-column dequant scales (4 per thread) --------------------------
  float scv[4];
#pragma unroll
  for (int g = 0; g < 4; ++g)
    scv[g] = scbuf[(jt + 16 * g) * 16 + col];

  // ---- h / c init ---------------------------------------------------------
  float carr;
  if (first) {
    for (int i = threadIdx.x; i < (2 * HB8_SZ) / 4; i += 1024)
      ((unsigned int*)hb0)[i] = 0u;
    carr = 0.0f;
  } else {
    const size_t idx = (size_t)(bg * 4 + bloc) * 256 + jt * 16 + col;
    carr = cstate[idx];
    const int qi = (int)rintf(hstate[idx] * 127.f);
    *(char*)(hb0 + bloc * HB8_ROW + jt * 16 + col) = (char)qi;
  }

  // ---- prefetch gx(t=0): one dwordx4 (4 gates) ---------------------------
  u32x4 gxA, gxB;
  {
    const unsigned int* g0 =
        gx + ((((size_t)0 * 16 + bg) * 8 + (jt >> 1)) << 8) + 4 * l;
    gxA = *(const u32x4*)g0;
  }
  __syncthreads();

  float* outp = out + (size_t)(bg * 4 + bloc) * 256 + col + jt * 16;
  const int aoff = ((l & 15) >> 2) * HB8_ROW + (l >> 4) * 16;  // A-frag read
  const int hwoff = bloc * HB8_ROW;
  const bool hi = (jt & 1) != 0;

  auto STEP = [&](int t, char* hbR, char* hbW, u32x4& gxC, u32x4& gxN) {
    // next-step gx prefetch: ONE dwordx4 (stays in flight across barrier)
    const int tn = (t + 1 < 512) ? (t + 1) : 511;
    const unsigned int* gn =
        gx + ((((size_t)tn * 16 + bg) * 8 + (jt >> 1)) << 8) + 4 * l;
    gxN = *(const u32x4*)gn;

    // A-frags (i8 h): 4 x ds_read_b128 covers K=256
    const char* hrd = hbR + aoff;
    i32x4 afv[4];
#pragma unroll
    for (int kt = 0; kt < 4; ++kt)
      afv[kt] = *(const i32x4*)(hrd + kt * 64);

    // ---- 4 gate chains x 4 kt, intrinsic MFMAs ----
    i32x4 d0 = {0, 0, 0, 0}, d1 = d0, d2 = d0, d3 = d0;
#pragma unroll
    for (int kt = 0; kt < 4; ++kt) {
      d0 = MFMA_I8(afv[kt], wa[kt], d0, 0, 0, 0);
      d1 = MFMA_I8(afv[kt], wa[4 + kt], d1, 0, 0, 0);
      d2 = MFMA_I8(afv[kt], wa[8 + kt], d2, 0, 0, 0);
      d3 = MFMA_I8(afv[kt], wa[12 + kt], d3, 0, 0, 0);
    }

    // epilogue: dequant -> gates -> c,h update -> global out + LDS i8 h
    {
      const float g0f = hi ? __uint_as_float(gxC[0] & 0xffff0000u)
                           : __uint_as_float(gxC[0] << 16);
      const float g1f = hi ? __uint_as_float(gxC[1] & 0xffff0000u)
                           : __uint_as_float(gxC[1] << 16);
      const float g2f = hi ? __uint_as_float(gxC[2] & 0xffff0000u)
                           : __uint_as_float(gxC[2] << 16);
      const float g3f = hi ? __uint_as_float(gxC[3] & 0xffff0000u)
                           : __uint_as_float(gxC[3] << 16);
      const float gi = sigmoid_scaled(fmaf((float)d0[0], scv[0], g0f));
      const float go = sigmoid_scaled(fmaf((float)d1[0], scv[1], g1f));
      const float gz = sigmoid_scaled(fmaf((float)d2[0], scv[2], g2f));
      const float gf = sigmoid_scaled(fmaf((float)d3[0], scv[3], g3f));
      carr = gf * carr + (gz - gi);
      const float hs = sigmoid_scaled(carr * NEG_LOG2E);
      const float hn = hs - go;
      outp[(size_t)t * 16384] = hn;
      const int qh = (int)rintf(hn * 127.f);
      *(char*)(hbW + hwoff + jt * 16 + col) = (char)qh;
    }

    // raw barrier: LDS-only drain (no "memory" clobber -> no vmcnt(0));
    // gx prefetch loads and out stores stay in flight across the barrier.
    __builtin_amdgcn_sched_barrier(0);
    asm volatile("s_waitcnt lgkmcnt(0)");
    __builtin_amdgcn_s_barrier();
    __builtin_amdgcn_sched_barrier(0);
  };

  for (int tt = 0; tt < 256; ++tt) {
    STEP(2 * tt, hb0, hb1, gxA, gxB);
    STEP(2 * tt + 1, hb1, hb0, gxB, gxA);
  }

  // ---- save state (h via i8 roundtrip == in-chunk path) -------------------
  {
    const size_t idx = (size_t)(bg * 4 + bloc) * 256 + jt * 16 + col;
    const signed char qv =
        *(const signed char*)(hb0 + hwoff + jt * 16 + col);
    hstate[idx] = (float)qv / 127.f;
    cstate[idx] = carr;
  }
}

// ===========================================================================
// Host launcher.  ws layout:
//   [0,256K)        wfq i8 frags
//   [256K,260K)     scbuf (1024 f32)
//   [260K,264K)     w127 (1024 f32)
//   [512K,576K)     hstate fp32 [64][256]
//   [576K,640K)     cstate fp32 [64][256]
//   [1M, 1M+64M)    gx chunk (512 steps, bf16-packed dwordx4 groups)
// ===========================================================================
extern "C" void kernel_launch(void* const* d_in, const int* in_sizes, int n_in,
                              void* d_out, int out_size, void* d_ws,
                              size_t ws_size, hipStream_t stream) {
  const float* x = (const float*)d_in[0];     // [2048][64][256]
  const float* w_in = (const float*)d_in[1];  // [1024][256]
  const float* bias = (const float*)d_in[2];  // [1024]
  const float* wrec = (const float*)d_in[3];  // [1024][256]
  float* out = (float*)d_out;                 // [2048][64][256]
  char* ws = (char*)d_ws;

  unsigned int* wfq = (unsigned int*)ws;
  float* scbuf = (float*)(ws + (256 << 10));
  float* w127 = (float*)(ws + (260 << 10));
  float* hstate = (float*)(ws + (512 << 10));
  float* cstate = (float*)(ws + (576 << 10));
  unsigned int* gxb = (unsigned int*)(ws + (1 << 20));

  (void)in_sizes; (void)n_in; (void)out_size; (void)ws_size;

  wscale_setup<<<dim3(1024), dim3(64), 0, stream>>>(wrec, scbuf, w127);
  wfrag_setup_i8<<<dim3(256), dim3(64), 0, stream>>>(wrec, w127, wfq);

  for (int c = 0; c < 4; ++c) {
    const size_t xoff = (size_t)c * 512 * 64 * 256;
    gemm_gx<<<dim3(2048), dim3(256), 0, stream>>>(x + xoff, w_in, bias, gxb);
    rnn_scan<<<dim3(16), dim3(1024), LDS_TOTAL, stream>>>(
        wfq, scbuf, gxb, out + xoff, hstate, cstate, (c == 0) ? 1 : 0);
  }
}

// Round 18
// 1719.711 us; speedup vs baseline: 1.2983x; 1.2337x over previous
//
#include <hip/hip_runtime.h>
#include <cstdint>
#include <cstddef>

typedef __attribute__((ext_vector_type(8))) short short8;
typedef __attribute__((ext_vector_type(4))) float f32x4;
typedef __attribute__((ext_vector_type(4))) unsigned int u32x4;
typedef __attribute__((ext_vector_type(4))) int i32x4;

#define NEG_LOG2E -1.44269504088896340736f
#define MFMA_BF16 __builtin_amdgcn_mfma_f32_16x16x32_bf16
#define MFMA_I8 __builtin_amdgcn_mfma_i32_16x16x64_i8
#define CH 256  // steps per chunk (8 chunks); gx double-buffer fits 65MB ws

// ---- helpers -------------------------------------------------------------
static __device__ __forceinline__ unsigned int cvt_pk_bf16(float lo, float hi) {
  unsigned int r;
  asm("v_cvt_pk_bf16_f32 %0, %1, %2" : "=v"(r) : "v"(lo), "v"(hi));
  return r;
}
// xs is pre-scaled by -log2(e): returns sigmoid(x_true)
static __device__ __forceinline__ float sigmoid_scaled(float xs) {
  return __builtin_amdgcn_rcpf(1.0f + __builtin_amdgcn_exp2f(xs));
}

// ---- fused-gemm 8-MFMA bf16 blobs (acc in AGPR, r5/r12-proven hazard
// discipline): chains c(mt,nt) for mt 0..3, nt 0..1 advance together per kt.
// "+&a" early-clobber acc (r6 lesson); first blob leads s_nop 3 (accvgpr
// zero-init -> SrcC); last blob trails 20-cyc nops (MFMA D -> accvgpr_read).
#define GMF8_BODY                                        \
  "v_mfma_f32_16x16x32_bf16 %0, %8, %12, %0\n\t"         \
  "v_mfma_f32_16x16x32_bf16 %1, %8, %13, %1\n\t"         \
  "v_mfma_f32_16x16x32_bf16 %2, %9, %12, %2\n\t"         \
  "v_mfma_f32_16x16x32_bf16 %3, %9, %13, %3\n\t"         \
  "v_mfma_f32_16x16x32_bf16 %4, %10, %12, %4\n\t"        \
  "v_mfma_f32_16x16x32_bf16 %5, %10, %13, %5\n\t"        \
  "v_mfma_f32_16x16x32_bf16 %6, %11, %12, %6\n\t"        \
  "v_mfma_f32_16x16x32_bf16 %7, %11, %13, %7"
#define GMF8_OUTS                                                          \
  "+&a"(c00), "+&a"(c01), "+&a"(c10), "+&a"(c11), "+&a"(c20), "+&a"(c21),  \
  "+&a"(c30), "+&a"(c31)
#define GMF8_INS                                                           \
  "v"(a0), "v"(a1), "v"(a2), "v"(a3), "v"(b0), "v"(b1)
#define DEF_GMF8(name, lead, tail)                                         \
  static __device__ __forceinline__ void name(                             \
      short8 a0, short8 a1, short8 a2, short8 a3, short8 b0, short8 b1,    \
      f32x4& c00, f32x4& c01, f32x4& c10, f32x4& c11, f32x4& c20,          \
      f32x4& c21, f32x4& c30, f32x4& c31) {                                \
    asm(lead GMF8_BODY tail : GMF8_OUTS : GMF8_INS);                       \
  }
DEF_GMF8(gmf8_first, "s_nop 3\n\t", "")
DEF_GMF8(gmf8_mid, "", "")
DEF_GMF8(gmf8_last, "", "\n\ts_nop 7\n\ts_nop 7\n\ts_nop 3")

// ===========================================================================
// Kernel 0: per-output-column scales (parallel).  scbuf[j] = s_j/(127*127),
// w127[j] = 127/s_j for column j of w' = w*NEG_LOG2E.
// ===========================================================================
__global__ void wscale_setup(const float* __restrict__ w_rec,
                             float* __restrict__ scbuf,
                             float* __restrict__ w127) {
  const int j = blockIdx.x;      // 0..1023
  const int l = threadIdx.x;     // 0..63
  const float* row = w_rec + (size_t)j * 256;
  float m = 0.f;
#pragma unroll
  for (int k = 0; k < 4; ++k) m = fmaxf(m, fabsf(row[l + 64 * k]));
#pragma unroll
  for (int d = 32; d > 0; d >>= 1) m = fmaxf(m, __shfl_xor(m, d));
  if (l == 0) {
    float s = fmaxf(m * 1.44269504088896f, 1e-30f);
    scbuf[j] = s / 16129.0f;
    w127[j] = 127.0f / s;
  }
}

// ===========================================================================
// Kernel 1: quantize w_rec -> i8 frags (r12-verified layout, unchanged).
// ===========================================================================
__global__ void wfrag_setup_i8(const float* __restrict__ w_rec,
                               const float* __restrict__ w127,
                               unsigned int* __restrict__ wfq) {
  const int f = blockIdx.x;   // 0..255
  const int l = threadIdx.x;  // 0..63
  const int w = f >> 6, q = f & 63;
  const int chain = q >> 2, kt = q & 3;
  const int jidx = chain >> 2, g = chain & 3;
  const int jt = (jidx < 2) ? (2 * w + jidx) : (2 * w + 8 + (jidx - 2));
  const int ct = jt + 16 * g;
  const int j = ct * 16 + (l & 15);
  const float r = w127[j];
  const float* src = w_rec + (size_t)j * 256 + kt * 64 + (l >> 4) * 16;
  u32x4 ov;
#pragma unroll
  for (int d = 0; d < 4; ++d) {
    unsigned int word = 0;
#pragma unroll
    for (int e = 0; e < 4; ++e) {
      int qi = (int)rintf(src[4 * d + e] * NEG_LOG2E * r);
      qi = qi > 127 ? 127 : (qi < -127 ? -127 : qi);
      word |= ((unsigned int)(qi & 255)) << (8 * e);
    }
    ov[d] = word;
  }
  *(u32x4*)(wfq + (size_t)f * 256 + (size_t)l * 4) = ov;
}

// ===========================================================================
// Kernel 2 (standalone, chunk 0 only): gx = (x@w_in^T + b)*-log2(e) in the
// r16-verified scan layout.  256-thread blocks, grid 1024 (128 row-tiles x
// 8 col-blocks), XCD decode bx=(n>>3)&7, by=(n>>6)*8+(n&7).
// ===========================================================================
static __device__ __forceinline__ short8 ldcvt8(const float* p) {
  f32x4 v0 = *(const f32x4*)p;
  f32x4 v1 = *(const f32x4*)(p + 4);
  u32x4 u;
  u[0] = cvt_pk_bf16(v0[0], v0[1]);
  u[1] = cvt_pk_bf16(v0[2], v0[3]);
  u[2] = cvt_pk_bf16(v1[0], v1[1]);
  u[3] = cvt_pk_bf16(v1[2], v1[3]);
  return __builtin_bit_cast(short8, u);
}

__global__ __launch_bounds__(256) void gemm_gx(const float* __restrict__ x,
                                               const float* __restrict__ w_in,
                                               const float* __restrict__ bias,
                                               unsigned int* __restrict__ gx) {
  const int n = blockIdx.x;               // 0..1023
  const int bx = (n >> 3) & 7;            // column block (8)
  const int by = (n >> 6) * 8 + (n & 7);  // row tile (128), xcd = n&7
  const int l = threadIdx.x & 63, wid = threadIdx.x >> 6;
  const int mq = wid >> 1, nq = wid & 1;
  const int mbase = by * 128 + mq * 64;
  const int nbase = bx * 128 + nq * 64;
  const int lr = l & 15;
  const int lk = (l >> 4) * 8;

  f32x4 acc[4][4] = {};
#pragma unroll
  for (int kt = 0; kt < 8; ++kt) {
    const int k0 = kt * 32 + lk;
    short8 af[4], bf[4];
#pragma unroll
    for (int mt = 0; mt < 4; ++mt)
      af[mt] = ldcvt8(x + (size_t)(mbase + mt * 16 + lr) * 256 + k0);
#pragma unroll
    for (int nt = 0; nt < 4; ++nt)
      bf[nt] = ldcvt8(w_in + (size_t)(nbase + nt * 16 + lr) * 256 + k0);
#pragma unroll
    for (int mt = 0; mt < 4; ++mt)
#pragma unroll
      for (int nt = 0; nt < 4; ++nt)
        acc[mt][nt] = MFMA_BF16(af[mt], bf[nt], acc[mt][nt], 0, 0, 0);
  }

  float bv[4];
#pragma unroll
  for (int nt = 0; nt < 4; ++nt) bv[nt] = bias[nbase + nt * 16 + lr];

#pragma unroll
  for (int mt = 0; mt < 4; ++mt) {
    const int m0 = mbase + mt * 16;
    const int tt = m0 >> 6;
    const int bg = ((m0 & 63) >> 2) + (l >> 4);
#pragma unroll
    for (int ntp = 0; ntp < 2; ++ntp) {
      const int p = (nbase >> 5) + ntp;
      const int pb = p & 7, g = p >> 3;
#pragma unroll
      for (int r = 0; r < 4; ++r) {
        float e0 = (acc[mt][ntp * 2 + 0][r] + bv[ntp * 2 + 0]) * NEG_LOG2E;
        float e1 = (acc[mt][ntp * 2 + 1][r] + bv[ntp * 2 + 1]) * NEG_LOG2E;
        gx[(((((size_t)tt * 16 + bg) * 8 + pb) * 64) + (r * 16 + lr)) * 4 + g] =
            cvt_pk_bf16(e0, e1);
      }
    }
  }
}

// ===========================================================================
// Kernel 3 (FUSED): blocks 0..15 = scan for chunk c (r17-verified structure,
// 16 waves, coltile jt = wave, 64 weight AGPRs, one raw s_barrier/step);
// blocks 16..527 = gemm for chunk c+1 into the other gx buffer (no sync
// needed: disjoint buffers; next launch's scan depends via kernel boundary).
// The scan uses 16 CUs; the gemm fills the other ~240 -> gemm time hidden.
// Gemm path: 512 blocks x 4 sub-groups(256thr) x 128x64 tile, acc in AGPR
// (32+ regs) so both paths fit the 1024-thread cap (<=128 unified regs).
// ===========================================================================
#define HB8_ROW 288                      // 256B h-row + 32B pad (2-way banks)
#define HB8_SZ (4 * HB8_ROW)             // 1152
#define LDS_TOTAL (2 * HB8_SZ)           // 2304

#define LD4A(i)                                                         \
  asm volatile("global_load_dwordx4 %0, %4, off\n\t"                    \
               "global_load_dwordx4 %1, %4, off offset:1024\n\t"        \
               "global_load_dwordx4 %2, %4, off offset:2048\n\t"        \
               "global_load_dwordx4 %3, %4, off offset:3072"            \
               : "=&a"(wa[4 * (i)]), "=&a"(wa[4 * (i) + 1]),            \
                 "=&a"(wa[4 * (i) + 2]), "=&a"(wa[4 * (i) + 3])         \
               : "v"(pA + 4096 * (i)))

__global__ __launch_bounds__(1024) void scan_gemm(
    const unsigned int* __restrict__ wfq, const float* __restrict__ scbuf,
    const unsigned int* __restrict__ gx, float* __restrict__ out,
    float* __restrict__ hstate, float* __restrict__ cstate, int first,
    const float* __restrict__ xn, const float* __restrict__ w_in,
    const float* __restrict__ bias, unsigned int* __restrict__ gxn,
    int do_gemm) {
  if (blockIdx.x >= 16) {
    // ------------------------- GEMM path (next chunk) ---------------------
    if (!do_gemm) return;
    const int mm = blockIdx.x - 16;          // 0..511
    const int by = mm >> 2;                  // 0..127 row tile
    const int sub = threadIdx.x >> 8;        // 0..3
    const int strip = ((mm & 3) << 2) + sub; // 0..15 (64-col strip)
    const int tix = threadIdx.x & 255;
    const int l = tix & 63, wid = tix >> 6;
    const int mq = wid >> 1, nq = wid & 1;
    const int mbase = by * 128 + mq * 64;
    const int nbase = strip * 64 + nq * 32;
    const int lr = l & 15, lk = (l >> 4) * 8;

    f32x4 c00 = {0.f, 0.f, 0.f, 0.f}, c01 = c00, c10 = c00, c11 = c00;
    f32x4 c20 = c00, c21 = c00, c30 = c00, c31 = c00;
#pragma unroll
    for (int kt = 0; kt < 8; ++kt) {
      const int k0 = kt * 32 + lk;
      const short8 a0 = ldcvt8(xn + (size_t)(mbase + 0 * 16 + lr) * 256 + k0);
      const short8 a1 = ldcvt8(xn + (size_t)(mbase + 1 * 16 + lr) * 256 + k0);
      const short8 a2 = ldcvt8(xn + (size_t)(mbase + 2 * 16 + lr) * 256 + k0);
      const short8 a3 = ldcvt8(xn + (size_t)(mbase + 3 * 16 + lr) * 256 + k0);
      const short8 b0 = ldcvt8(w_in + (size_t)(nbase + 0 * 16 + lr) * 256 + k0);
      const short8 b1 = ldcvt8(w_in + (size_t)(nbase + 1 * 16 + lr) * 256 + k0);
      if (kt == 0)
        gmf8_first(a0, a1, a2, a3, b0, b1, c00, c01, c10, c11, c20, c21, c30, c31);
      else if (kt < 7)
        gmf8_mid(a0, a1, a2, a3, b0, b1, c00, c01, c10, c11, c20, c21, c30, c31);
      else
        gmf8_last(a0, a1, a2, a3, b0, b1, c00, c01, c10, c11, c20, c21, c30, c31);
    }

    const float bv0 = bias[nbase + lr];
    const float bv1 = bias[nbase + 16 + lr];
    const int p = nbase >> 5;           // = strip*2 + nq
    const int pb = p & 7, g = p >> 3;
    const f32x4* accm[4][2] = {{&c00, &c01}, {&c10, &c11},
                               {&c20, &c21}, {&c30, &c31}};
#pragma unroll
    for (int mt = 0; mt < 4; ++mt) {
      const int m0 = mbase + mt * 16;
      const int tt = m0 >> 6;
      const int bg = ((m0 & 63) >> 2) + (l >> 4);
#pragma unroll
      for (int r = 0; r < 4; ++r) {
        float e0 = ((*accm[mt][0])[r] + bv0) * NEG_LOG2E;
        float e1 = ((*accm[mt][1])[r] + bv1) * NEG_LOG2E;
        gxn[(((((size_t)tt * 16 + bg) * 8 + pb) * 64) + (r * 16 + lr)) * 4 + g] =
            cvt_pk_bf16(e0, e1);
      }
    }
    return;
  }

  // --------------------------- SCAN path (chunk c) ------------------------
  extern __shared__ char lds[];
  char* hb0 = lds;
  char* hb1 = lds + HB8_SZ;

  const int l = threadIdx.x & 63;
  const int w = threadIdx.x >> 6;   // 0..15 -> coltile jt = w
  const int bg = blockIdx.x;        // 0..15 -> batches 4bg..4bg+3
  const int bloc = l >> 4;          // local batch 0..3
  const int col = l & 15;
  const int jt = w;
  const int fbase = (jt < 8) ? ((jt >> 1) * 64 + (jt & 1) * 16)
                             : (((jt - 8) >> 1) * 64 + (2 + (jt & 1)) * 16);

  // ---- 16 weight frags -> AGPR (64 regs); contiguous 16KB region ---------
  i32x4 wa[16];
  {
    const char* pA = (const char*)wfq + (size_t)fbase * 1024 + (size_t)l * 16;
    LD4A(0); LD4A(1); LD4A(2); LD4A(3);
    asm volatile("s_waitcnt vmcnt(0)" ::: "memory");
  }
  // ---- per-column dequant scales (4 per thread) --------------------------
  float scv[4];
#pragma unroll
  for (int g = 0; g < 4; ++g)
    scv[g] = scbuf[(jt + 16 * g) * 16 + col];

  // ---- h / c init ---------------------------------------------------------
  float carr;
  if (first) {
    for (int i = threadIdx.x; i < (2 * HB8_SZ) / 4; i += 1024)
      ((unsigned int*)hb0)[i] = 0u;
    carr = 0.0f;
  } else {
    const size_t idx = (size_t)(bg * 4 + bloc) * 256 + jt * 16 + col;
    carr = cstate[idx];
    const int qi = (int)rintf(hstate[idx] * 127.f);
    *(char*)(hb0 + bloc * HB8_ROW + jt * 16 + col) = (char)qi;
  }

  // ---- prefetch gx(t=0): one dwordx4 (4 gates) ---------------------------
  u32x4 gxA, gxB;
  {
    const unsigned int* g0 =
        gx + ((((size_t)0 * 16 + bg) * 8 + (jt >> 1)) << 8) + 4 * l;
    gxA = *(const u32x4*)g0;
  }
  __syncthreads();

  float* outp = out + (size_t)(bg * 4 + bloc) * 256 + col + jt * 16;
  const int aoff = ((l & 15) >> 2) * HB8_ROW + (l >> 4) * 16;  // A-frag read
  const int hwoff = bloc * HB8_ROW;
  const bool hi = (jt & 1) != 0;

  auto STEP = [&](int t, char* hbR, char* hbW, u32x4& gxC, u32x4& gxN) {
    // next-step gx prefetch: ONE dwordx4 (stays in flight across barrier)
    const int tn = (t + 1 < CH) ? (t + 1) : (CH - 1);
    const unsigned int* gn =
        gx + ((((size_t)tn * 16 + bg) * 8 + (jt >> 1)) << 8) + 4 * l;
    gxN = *(const u32x4*)gn;

    // A-frags (i8 h): 4 x ds_read_b128 covers K=256
    const char* hrd = hbR + aoff;
    i32x4 afv[4];
#pragma unroll
    for (int kt = 0; kt < 4; ++kt)
      afv[kt] = *(const i32x4*)(hrd + kt * 64);

    // ---- 4 gate chains x 4 kt, intrinsic MFMAs ----
    i32x4 d0 = {0, 0, 0, 0}, d1 = d0, d2 = d0, d3 = d0;
#pragma unroll
    for (int kt = 0; kt < 4; ++kt) {
      d0 = MFMA_I8(afv[kt], wa[kt], d0, 0, 0, 0);
      d1 = MFMA_I8(afv[kt], wa[4 + kt], d1, 0, 0, 0);
      d2 = MFMA_I8(afv[kt], wa[8 + kt], d2, 0, 0, 0);
      d3 = MFMA_I8(afv[kt], wa[12 + kt], d3, 0, 0, 0);
    }

    // epilogue: dequant -> gates -> c,h update -> global out + LDS i8 h
    {
      const float g0f = hi ? __uint_as_float(gxC[0] & 0xffff0000u)
                           : __uint_as_float(gxC[0] << 16);
      const float g1f = hi ? __uint_as_float(gxC[1] & 0xffff0000u)
                           : __uint_as_float(gxC[1] << 16);
      const float g2f = hi ? __uint_as_float(gxC[2] & 0xffff0000u)
                           : __uint_as_float(gxC[2] << 16);
      const float g3f = hi ? __uint_as_float(gxC[3] & 0xffff0000u)
                           : __uint_as_float(gxC[3] << 16);
      const float gi = sigmoid_scaled(fmaf((float)d0[0], scv[0], g0f));
      const float go = sigmoid_scaled(fmaf((float)d1[0], scv[1], g1f));
      const float gz = sigmoid_scaled(fmaf((float)d2[0], scv[2], g2f));
      const float gf = sigmoid_scaled(fmaf((float)d3[0], scv[3], g3f));
      carr = gf * carr + (gz - gi);
      const float hs = sigmoid_scaled(carr * NEG_LOG2E);
      const float hn = hs - go;
      outp[(size_t)t * 16384] = hn;
      const int qh = (int)rintf(hn * 127.f);
      *(char*)(hbW + hwoff + jt * 16 + col) = (char)qh;
    }

    // raw barrier: LDS-only drain (no "memory" clobber -> no vmcnt(0));
    // gx prefetch loads and out stores stay in flight across the barrier.
    __builtin_amdgcn_sched_barrier(0);
    asm volatile("s_waitcnt lgkmcnt(0)");
    __builtin_amdgcn_s_barrier();
    __builtin_amdgcn_sched_barrier(0);
  };

  for (int tt = 0; tt < CH / 2; ++tt) {
    STEP(2 * tt, hb0, hb1, gxA, gxB);
    STEP(2 * tt + 1, hb1, hb0, gxB, gxA);
  }

  // ---- save state (h via i8 roundtrip == in-chunk path) -------------------
  {
    const size_t idx = (size_t)(bg * 4 + bloc) * 256 + jt * 16 + col;
    const signed char qv =
        *(const signed char*)(hb0 + hwoff + jt * 16 + col);
    hstate[idx] = (float)qv / 127.f;
    cstate[idx] = carr;
  }
}

// ===========================================================================
// Host launcher.  ws layout:
//   [0,256K)        wfq i8 frags
//   [256K,260K)     scbuf (1024 f32)
//   [260K,264K)     w127 (1024 f32)
//   [512K,576K)     hstate fp32 [64][256]
//   [576K,640K)     cstate fp32 [64][256]
//   [1M, 33M)       gx buffer 0 (256 steps)
//   [33M, 65M)      gx buffer 1 (256 steps)
// 8 chunks of 256 steps; gemm(c+1) fused into scan(c) launch (double-buffer).
// ===========================================================================
extern "C" void kernel_launch(void* const* d_in, const int* in_sizes, int n_in,
                              void* d_out, int out_size, void* d_ws,
                              size_t ws_size, hipStream_t stream) {
  const float* x = (const float*)d_in[0];     // [2048][64][256]
  const float* w_in = (const float*)d_in[1];  // [1024][256]
  const float* bias = (const float*)d_in[2];  // [1024]
  const float* wrec = (const float*)d_in[3];  // [1024][256]
  float* out = (float*)d_out;                 // [2048][64][256]
  char* ws = (char*)d_ws;

  unsigned int* wfq = (unsigned int*)ws;
  float* scbuf = (float*)(ws + (256 << 10));
  float* w127 = (float*)(ws + (260 << 10));
  float* hstate = (float*)(ws + (512 << 10));
  float* cstate = (float*)(ws + (576 << 10));
  unsigned int* gxb[2] = {(unsigned int*)(ws + (1ull << 20)),
                          (unsigned int*)(ws + (33ull << 20))};

  (void)in_sizes; (void)n_in; (void)out_size; (void)ws_size;

  wscale_setup<<<dim3(1024), dim3(64), 0, stream>>>(wrec, scbuf, w127);
  wfrag_setup_i8<<<dim3(256), dim3(64), 0, stream>>>(wrec, w127, wfq);

  const size_t chelt = (size_t)CH * 64 * 256;
  gemm_gx<<<dim3(1024), dim3(256), 0, stream>>>(x, w_in, bias, gxb[0]);

  for (int c = 0; c < 8; ++c) {
    const int nxt = (c + 1 < 8) ? (c + 1) : 0;
    scan_gemm<<<dim3(16 + 512), dim3(1024), LDS_TOTAL, stream>>>(
        wfq, scbuf, gxb[c & 1], out + (size_t)c * chelt, hstate, cstate,
        (c == 0) ? 1 : 0, x + (size_t)nxt * chelt, w_in, bias,
        gxb[(c + 1) & 1], (c < 7) ? 1 : 0);
  }
}